// Round 13
// baseline (328.873 us; speedup 1.0000x reference)
//
#include <hip/hip_runtime.h>
#include <math.h>

// ---------------------------------------------------------------------------
// Restormer-style TransformerBlock on MI355X (gfx950)
// B=4, C=192, H=W=128, N=HW=16384, heads=8, ch/head=24, hidden=510
// Intermediates: y/xb/out1b/y3/qkvd/g bf16 [B][N][C]; qkv/h fp8-e4m3 (OCP).
// Residual: x fp32 [C][N] in, d_out fp32 [C][N]. LN3 fused into K6.
// ---------------------------------------------------------------------------

typedef __attribute__((ext_vector_type(8))) short short8;
typedef __attribute__((ext_vector_type(4))) short short4v;
typedef __attribute__((ext_vector_type(4))) float f32x4;
typedef __attribute__((ext_vector_type(2))) float f32x2;
typedef __attribute__((ext_vector_type(2))) unsigned uint2v;

#define DEVI __device__ __forceinline__

DEVI unsigned short f2bf(float f) {
  union { float f; unsigned u; } v; v.f = f;
  unsigned r = v.u + 0x7fffu + ((v.u >> 16) & 1u);   // RNE
  return (unsigned short)(r >> 16);
}
DEVI float bf2f(unsigned short h) {
  union { unsigned u; float f; } v; v.u = ((unsigned)h) << 16;
  return v.f;
}
// branch-free GELU, exp2-folded tanh form; inf-safe (e=inf -> rcp=0 -> x*1)
DEVI float gelu_f(float x) {
  float t = x * (2.30258509f + 0.10296501f * x * x);
  float e = exp2f(t);
  return x * (1.f - __builtin_amdgcn_rcpf(e + 1.f));
}

// ---------------------------------------------------------------------------
// K0: convert + zero-pad weights to bf16; pack dw-conv weights.
//  dwq [144 g][9 q][4 j] f32 ; wf8 [128 g][9 q][8 sj] bf16 (ch>=510 -> 0)
// ---------------------------------------------------------------------------
__global__ __launch_bounds__(256) void k_convert_w(
    const float* __restrict__ qkv_w, const float* __restrict__ ffn_in_w,
    const float* __restrict__ ffn_out_w, const float* __restrict__ qkv_dw_w,
    const float* __restrict__ ffn_dw_w,
    unsigned short* __restrict__ wq, unsigned short* __restrict__ wi,
    unsigned short* __restrict__ wo, float* __restrict__ dwq,
    unsigned short* __restrict__ wf8) {
  int idx = blockIdx.x * 256 + threadIdx.x;
  if (idx < 576 * 192) wq[idx] = f2bf(qkv_w[idx]);
  if (idx < 1024 * 192) {
    int o = idx / 192, c = idx - o * 192;
    int src = (o < 510) ? o : ((o >= 512 && o < 1022) ? o - 2 : -1);
    wi[idx] = (src >= 0) ? f2bf(ffn_in_w[src * 192 + c]) : (unsigned short)0;
  }
  if (idx < 192 * 512) {
    int o = idx >> 9, c = idx & 511;
    wo[idx] = (c < 510) ? f2bf(ffn_out_w[o * 510 + c]) : (unsigned short)0;
  }
  if (idx < 144 * 36) {
    int g = idx / 36, r = idx - g * 36;
    int q = r >> 2, j = r & 3;
    dwq[idx] = qkv_dw_w[(g * 4 + j) * 9 + q];
  }
  if (idx < 128 * 72) {
    int g = idx / 72, r = idx - g * 72;
    int q = r >> 3, sj = r & 7, s = sj >> 2, j = sj & 3;
    int ch = g * 4 + j;
    wf8[idx] = (ch < 510) ? f2bf(ffn_dw_w[(s ? 510 + ch : ch) * 9 + q])
                          : (unsigned short)0;
  }
}

__global__ __launch_bounds__(256) void k_zero(float* __restrict__ p, int n) {
  int i = blockIdx.x * 256 + threadIdx.x;
  if (i < n) p[i] = 0.f;
}

// ---------------------------------------------------------------------------
// LN2: fp32 [B][192][N] -> y bf16 [B][N][192]; also emits xb = bf16(x).
// ---------------------------------------------------------------------------
__global__ __launch_bounds__(256) void k_ln(
    const float* __restrict__ x, const float* __restrict__ g,
    const float* __restrict__ bta, unsigned short* __restrict__ y,
    unsigned short* __restrict__ xb) {
  int idx = blockIdx.x * 256 + threadIdx.x;   // 2 * B*N = 131072
  int half = idx & 1;
  int n = idx >> 1;
  int b = n >> 14, nn = n & 16383;
  int c0 = half * 96;
  const float* px = x + (((size_t)b * 192 + c0) << 14) + nn;
  float v[96];
  float s = 0.f, ss = 0.f;
#pragma unroll
  for (int j = 0; j < 96; j++) {
    v[j] = px[(size_t)j << 14];
    s += v[j]; ss += v[j] * v[j];
  }
  s += __shfl_xor(s, 1, 64);
  ss += __shfl_xor(ss, 1, 64);
  float mu = s * (1.f / 192.f);
  float var = ss * (1.f / 192.f) - mu * mu;
  float rs = rsqrtf(var + 1e-5f);
  size_t rowb = ((((size_t)b << 14) + nn) * 192) + c0;
  unsigned short* py = y + rowb;
  unsigned short* pxb = xb + rowb;
#pragma unroll
  for (int j8 = 0; j8 < 12; j8++) {
    short8 o8, x8;
#pragma unroll
    for (int k = 0; k < 8; k++) {
      int c = c0 + j8 * 8 + k;
      float f = v[j8 * 8 + k];
      o8[k] = (short)f2bf((f - mu) * rs * g[c] + bta[c]);
      x8[k] = (short)f2bf(f);
    }
    *reinterpret_cast<short8*>(py + j8 * 8) = o8;
    *reinterpret_cast<short8*>(pxb + j8 * 8) = x8;
  }
}

// ---------------------------------------------------------------------------
// GEMM: out[o][n] = sum_c W[o][c] * in[n][c]
//  EPI 0: bf16 store to out[N][rsout]
//  EPI 3: fp32 store d_out[(b*192+o)<<14|nn] = bf2f(residB[n*192+o]) + acc
//  EPI 4: fp8 (e4m3) store to out[N][rsout] (rsout in bytes)
// ---------------------------------------------------------------------------
template <int C, int OCHUNK, int NB, int EPI>
__global__ __launch_bounds__(512) void k_gemm(
    const unsigned short* __restrict__ in, int rsin,
    const unsigned short* __restrict__ W, int wbs,
    const float* __restrict__ residF, const unsigned short* __restrict__ residB,
    void* __restrict__ outp, int rsout) {
  constexpr int SLOTS = C / 8;
  __shared__ unsigned short lds[OCHUNK * C];
  int t = threadIdx.x;
  int b = blockIdx.z;
  int ocb = blockIdx.y * OCHUNK;
  int wv = t >> 6, lane = t & 63, lrow = lane & 15, lhi = lane >> 4;

  const unsigned short* Wb = W + (size_t)b * wbs;
#pragma unroll
  for (int i = t; i < OCHUNK * SLOTS; i += 512) {
    int o = i / SLOTS, s = i - o * SLOTS;
    short8 v = *reinterpret_cast<const short8*>(&Wb[(size_t)(ocb + o) * C + s * 8]);
    *reinterpret_cast<short8*>(&lds[(o * SLOTS + (s ^ (o & 7))) * 8]) = v;
  }

  size_t nbase = ((size_t)b << 14) + blockIdx.x * (128 * NB) + wv * (16 * NB);
  short8 bf[NB][C / 32];
#pragma unroll
  for (int nb = 0; nb < NB; nb++) {
    const unsigned short* prow = in + (nbase + nb * 16 + lrow) * rsin + lhi * 8;
#pragma unroll
    for (int k = 0; k < C / 32; k++)
      bf[nb][k] = *reinterpret_cast<const short8*>(prow + k * 32);
  }
  __syncthreads();

  for (int ot = 0; ot < OCHUNK / 16; ++ot) {
    f32x4 acc[NB];
#pragma unroll
    for (int nb = 0; nb < NB; nb++) acc[nb] = (f32x4){0.f, 0.f, 0.f, 0.f};
    int orow = ot * 16 + lrow;
#pragma unroll
    for (int k = 0; k < C / 32; k++) {
      short8 a = *reinterpret_cast<const short8*>(
          &lds[(orow * SLOTS + ((k * 4 + lhi) ^ (lrow & 7))) * 8]);
#pragma unroll
      for (int nb = 0; nb < NB; nb++)
        acc[nb] = __builtin_amdgcn_mfma_f32_16x16x32_bf16(a, bf[nb][k], acc[nb], 0, 0, 0);
    }
#pragma unroll
    for (int nb = 0; nb < NB; nb++) {
      size_t n = nbase + nb * 16 + lrow;   // includes b*16384
      int obase = ocb + ot * 16 + lhi * 4;
      if (EPI == 0) {
        short4v pk;
#pragma unroll
        for (int r = 0; r < 4; r++) pk[r] = (short)f2bf(acc[nb][r]);
        *reinterpret_cast<short4v*>((unsigned short*)outp + n * rsout + obase) = pk;
      } else if (EPI == 4) {
        int u = 0;
        u = __builtin_amdgcn_cvt_pk_fp8_f32(acc[nb][0], acc[nb][1], u, false);
        u = __builtin_amdgcn_cvt_pk_fp8_f32(acc[nb][2], acc[nb][3], u, true);
        *reinterpret_cast<int*>((unsigned char*)outp + n * (size_t)rsout + obase) = u;
      } else {   // EPI == 3
        int nn = (int)(n & 16383);
        short4v rb = *reinterpret_cast<const short4v*>(residB + n * 192 + obase);
#pragma unroll
        for (int r = 0; r < 4; r++) {
          size_t idx = (((size_t)(b * 192 + obase + r)) << 14) + nn;
          ((float*)outp)[idx] = bf2f((unsigned short)rb[r]) + acc[nb][r];
        }
      }
    }
  }
}

// ---------------------------------------------------------------------------
// K6: z = M[b] @ v + xb ; out1b = bf16(z) ; y3 = bf16(LN3(z)).  LN3 once.
// Wave = 16 n-rows; grid (128 n-splits, 4 b), 512 thr (8 waves).
// ---------------------------------------------------------------------------
__global__ __launch_bounds__(512) void k_gemm6(
    const unsigned short* __restrict__ in,    // v rows: qkvd+384, rsin=576
    const unsigned short* __restrict__ Mw,    // [b][192][192]
    const unsigned short* __restrict__ xb,    // bf16 [B*N][192] residual
    const float* __restrict__ lg, const float* __restrict__ lb,
    unsigned short* __restrict__ out1b,       // [B*N][192]
    unsigned short* __restrict__ y3) {        // [B*N][192]
  constexpr int SLOTS = 24;
  __shared__ unsigned short lds[192 * 192];
  int t = threadIdx.x;
  int b = blockIdx.y;
  int wv = t >> 6, lane = t & 63, lrow = lane & 15, lhi = lane >> 4;

  const unsigned short* Wb = Mw + (size_t)b * 192 * 192;
#pragma unroll
  for (int i = t; i < 192 * SLOTS; i += 512) {
    int o = i / SLOTS, s = i - o * SLOTS;
    short8 v = *reinterpret_cast<const short8*>(&Wb[o * 192 + s * 8]);
    *reinterpret_cast<short8*>(&lds[(o * SLOTS + (s ^ (o & 7))) * 8]) = v;
  }

  size_t nbase = ((size_t)b << 14) + blockIdx.x * 128 + wv * 16;
  short8 bf[6];
  {
    const unsigned short* prow = in + (nbase + lrow) * 576 + lhi * 8;
#pragma unroll
    for (int k = 0; k < 6; k++)
      bf[k] = *reinterpret_cast<const short8*>(prow + k * 32);
  }
  __syncthreads();

  short4v zs[12];
  float s = 0.f, ss = 0.f;
#pragma unroll
  for (int ot = 0; ot < 12; ++ot) {
    f32x4 acc = (f32x4){0.f, 0.f, 0.f, 0.f};
    int orow = ot * 16 + lrow;
#pragma unroll
    for (int k = 0; k < 6; k++) {
      short8 a = *reinterpret_cast<const short8*>(
          &lds[(orow * SLOTS + ((k * 4 + lhi) ^ (lrow & 7))) * 8]);
      acc = __builtin_amdgcn_mfma_f32_16x16x32_bf16(a, bf[k], acc, 0, 0, 0);
    }
    int obase = ot * 16 + lhi * 4;
    size_t n = nbase + lrow;
    short4v xv = *reinterpret_cast<const short4v*>(xb + n * 192 + obase);
    short4v pk;
#pragma unroll
    for (int r = 0; r < 4; r++) {
      float val = bf2f((unsigned short)xv[r]) + acc[r];
      s += val; ss += val * val;
      pk[r] = (short)f2bf(val);
    }
    *reinterpret_cast<short4v*>(out1b + n * 192 + obase) = pk;
    zs[ot] = pk;
  }

  s += __shfl_xor(s, 16, 64);  s += __shfl_xor(s, 32, 64);
  ss += __shfl_xor(ss, 16, 64); ss += __shfl_xor(ss, 32, 64);
  float mu = s * (1.f / 192.f);
  float var = ss * (1.f / 192.f) - mu * mu;
  float rs = rsqrtf(var + 1e-5f);
#pragma unroll
  for (int ot = 0; ot < 12; ++ot) {
    int c0 = ot * 16 + lhi * 4;
    f32x4 g4 = *reinterpret_cast<const f32x4*>(lg + c0);
    f32x4 b4 = *reinterpret_cast<const f32x4*>(lb + c0);
    size_t n = nbase + lrow;
    short4v pk;
#pragma unroll
    for (int r = 0; r < 4; r++) {
      float f = bf2f((unsigned short)zs[ot][r]);
      pk[r] = (short)f2bf((f - mu) * rs * g4[r] + b4[r]);
    }
    *reinterpret_cast<short4v*>(y3 + n * 192 + c0) = pk;
  }
}

// ---------------------------------------------------------------------------
// Depthwise 3x3 (pad 1) for qkv path: in fp8 [N][576B], out bf16 [N][576].
// Thread = 4 ch x 4 w x 2 h. Lane dim = channel group (coalesced).
// ---------------------------------------------------------------------------
__global__ __launch_bounds__(256) void k_dwq(
    const unsigned char* __restrict__ in, const float* __restrict__ wp,
    unsigned short* __restrict__ out) {
  constexpr int RSI = 576;   // bytes per n-row
  int idx = blockIdx.x * 256 + threadIdx.x;   // 144 g * 32 w4 * 64 h2 * 4 b
  int g = idx % 144;
  int rest = idx / 144;
  int w4 = rest & 31, h2 = (rest >> 5) & 63, b = rest >> 11;
  int h0 = h2 * 2, w0 = w4 * 4, ch0 = g * 4;
  bool vm = (h0 > 0), vp = (h0 < 126);
  bool zl = (w4 == 0), zr = (w4 == 31);

  const unsigned char* p1 = in + (((size_t)b << 14) + h0 * 128 + w0) * RSI + ch0;
  const unsigned char* pr0 = vm ? p1 - 128 * RSI : p1;
  const unsigned char* pr2 = p1 + 128 * RSI;
  const unsigned char* pr3 = vp ? p1 + 256 * RSI : p1;

  unsigned m[4][6];
#pragma unroll
  for (int k = 0; k < 6; k++) {
    m[0][k] = *reinterpret_cast<const unsigned*>(pr0 + (k - 1) * RSI);
    m[1][k] = *reinterpret_cast<const unsigned*>(p1 + (k - 1) * RSI);
    m[2][k] = *reinterpret_cast<const unsigned*>(pr2 + (k - 1) * RSI);
    m[3][k] = *reinterpret_cast<const unsigned*>(pr3 + (k - 1) * RSI);
  }
  f32x4 wv4[9];
#pragma unroll
  for (int q = 0; q < 9; q++)
    wv4[q] = *reinterpret_cast<const f32x4*>(&wp[(g * 9 + q) * 4]);

  if (!vm) {
#pragma unroll
    for (int k = 0; k < 6; k++) m[0][k] = 0u;
  }
  if (!vp) {
#pragma unroll
    for (int k = 0; k < 6; k++) m[3][k] = 0u;
  }
  if (zl) {
#pragma unroll
    for (int r = 0; r < 4; r++) m[r][0] = 0u;
  }
  if (zr) {
#pragma unroll
    for (int r = 0; r < 4; r++) m[r][5] = 0u;
  }

  f32x2 acc[2][4][2];
#pragma unroll
  for (int ho = 0; ho < 2; ho++)
#pragma unroll
    for (int wo = 0; wo < 4; wo++)
#pragma unroll
      for (int p = 0; p < 2; p++) acc[ho][wo][p] = (f32x2){0.f, 0.f};

#pragma unroll
  for (int r = 0; r < 4; r++) {
    f32x2 f[6][2];
#pragma unroll
    for (int k = 0; k < 6; k++) {
      f[k][0] = __builtin_amdgcn_cvt_pk_f32_fp8((int)m[r][k], false);
      f[k][1] = __builtin_amdgcn_cvt_pk_f32_fp8((int)m[r][k], true);
    }
#pragma unroll
    for (int ho = 0; ho < 2; ho++) {
      int dh = r - ho;
      if (dh < 0 || dh > 2) continue;   // folds at compile time
#pragma unroll
      for (int dw = 0; dw < 3; dw++) {
        f32x4 w4v = wv4[dh * 3 + dw];
        f32x2 wa = {w4v[0], w4v[1]}, wb = {w4v[2], w4v[3]};
#pragma unroll
        for (int wo = 0; wo < 4; wo++) {
          acc[ho][wo][0] += wa * f[wo + dw][0];
          acc[ho][wo][1] += wb * f[wo + dw][1];
        }
      }
    }
  }

  unsigned short* ob = out + (((size_t)b << 14) + h0 * 128 + w0) * 576 + ch0;
#pragma unroll
  for (int ho = 0; ho < 2; ho++)
#pragma unroll
    for (int wo = 0; wo < 4; wo++) {
      short4v o4;
      o4[0] = (short)f2bf(acc[ho][wo][0].x);
      o4[1] = (short)f2bf(acc[ho][wo][0].y);
      o4[2] = (short)f2bf(acc[ho][wo][1].x);
      o4[3] = (short)f2bf(acc[ho][wo][1].y);
      *reinterpret_cast<short4v*>(ob + (ho * 128 + wo) * 576) = o4;
    }
}

// ---------------------------------------------------------------------------
// Depthwise 3x3 + GELU gate for FFN: in fp8 [N][1024B] cols c & 512+c
// -> out bf16 [N][512]. Thread = 4 ch x 2 w x 2 h, both sets.
// ---------------------------------------------------------------------------
__global__ __launch_bounds__(256) void k_dwf(
    const unsigned char* __restrict__ in, const unsigned short* __restrict__ wp8,
    unsigned short* __restrict__ out) {
  constexpr int RSI = 1024;   // bytes per n-row
  int idx = blockIdx.x * 256 + threadIdx.x;   // 128 g * 64 w2 * 64 h2 * 4 b
  int g = idx & 127;
  int rest = idx >> 7;
  int w2 = rest & 63, h2 = (rest >> 6) & 63, b = rest >> 12;
  int w0 = w2 * 2, h0 = h2 * 2, ch0 = g * 4;
  bool vm = (h0 > 0), vp = (h0 < 126);
  bool zl = (w2 == 0), zr = (w2 == 63);

  const unsigned char* p1 = in + (((size_t)b << 14) + h0 * 128 + w0) * RSI + ch0;
  const unsigned char* pr0 = vm ? p1 - 128 * RSI : p1;
  const unsigned char* pr2 = p1 + 128 * RSI;
  const unsigned char* pr3 = vp ? p1 + 256 * RSI : p1;

  unsigned m[2][4][4];   // [set][row][wchunk: w-1..w+2]
#pragma unroll
  for (int s = 0; s < 2; s++) {
    int co = s * 512;
#pragma unroll
    for (int k = 0; k < 4; k++) {
      m[s][0][k] = *reinterpret_cast<const unsigned*>(pr0 + (k - 1) * RSI + co);
      m[s][1][k] = *reinterpret_cast<const unsigned*>(p1 + (k - 1) * RSI + co);
      m[s][2][k] = *reinterpret_cast<const unsigned*>(pr2 + (k - 1) * RSI + co);
      m[s][3][k] = *reinterpret_cast<const unsigned*>(pr3 + (k - 1) * RSI + co);
    }
  }
#pragma unroll
  for (int s = 0; s < 2; s++) {
    if (!vm) {
#pragma unroll
      for (int k = 0; k < 4; k++) m[s][0][k] = 0u;
    }
    if (!vp) {
#pragma unroll
      for (int k = 0; k < 4; k++) m[s][3][k] = 0u;
    }
    if (zl) {
#pragma unroll
      for (int r = 0; r < 4; r++) m[s][r][0] = 0u;
    }
    if (zr) {
#pragma unroll
      for (int r = 0; r < 4; r++) m[s][r][3] = 0u;
    }
  }

  f32x2 acc1[2][2][2], acc2[2][2][2];   // [ho][wo][pair]
#pragma unroll
  for (int ho = 0; ho < 2; ho++)
#pragma unroll
    for (int wo = 0; wo < 2; wo++)
#pragma unroll
      for (int p = 0; p < 2; p++) {
        acc1[ho][wo][p] = (f32x2){0.f, 0.f};
        acc2[ho][wo][p] = (f32x2){0.f, 0.f};
      }

#pragma unroll
  for (int s = 0; s < 2; s++) {
#pragma unroll
    for (int r = 0; r < 4; r++) {
      f32x2 f[4][2];
#pragma unroll
      for (int k = 0; k < 4; k++) {
        f[k][0] = __builtin_amdgcn_cvt_pk_f32_fp8((int)m[s][r][k], false);
        f[k][1] = __builtin_amdgcn_cvt_pk_f32_fp8((int)m[s][r][k], true);
      }
#pragma unroll
      for (int ho = 0; ho < 2; ho++) {
        int dh = r - ho;
        if (dh < 0 || dh > 2) continue;
#pragma unroll
        for (int dw = 0; dw < 3; dw++) {
          int q = dh * 3 + dw;
          short4v wr = *reinterpret_cast<const short4v*>(
              wp8 + (g * 9 + q) * 8 + s * 4);
          f32x2 wa = {bf2f((unsigned short)wr[0]), bf2f((unsigned short)wr[1])};
          f32x2 wb = {bf2f((unsigned short)wr[2]), bf2f((unsigned short)wr[3])};
#pragma unroll
          for (int wo = 0; wo < 2; wo++) {
            if (s == 0) {
              acc1[ho][wo][0] += wa * f[wo + dw][0];
              acc1[ho][wo][1] += wb * f[wo + dw][1];
            } else {
              acc2[ho][wo][0] += wa * f[wo + dw][0];
              acc2[ho][wo][1] += wb * f[wo + dw][1];
            }
          }
        }
      }
    }
  }

  unsigned short* ob = out + (((size_t)b << 14) + h0 * 128 + w0) * 512 + ch0;
#pragma unroll
  for (int ho = 0; ho < 2; ho++)
#pragma unroll
    for (int wo = 0; wo < 2; wo++) {
      float x1v[4] = {acc1[ho][wo][0].x, acc1[ho][wo][0].y,
                      acc1[ho][wo][1].x, acc1[ho][wo][1].y};
      float x2v[4] = {acc2[ho][wo][0].x, acc2[ho][wo][0].y,
                      acc2[ho][wo][1].x, acc2[ho][wo][1].y};
      short4v o4;
#pragma unroll
      for (int j = 0; j < 4; j++)
        o4[j] = (short)f2bf(gelu_f(x1v[j]) * x2v[j]);
      *reinterpret_cast<short4v*>(ob + (ho * 128 + wo) * 512) = o4;
    }
}

// ---------------------------------------------------------------------------
// Gram: G[b][h][48][48] += stacked.stacked^T (rows [q_h;k_h]), over n.
// ---------------------------------------------------------------------------
__global__ __launch_bounds__(256) void k_gram(
    const unsigned short* __restrict__ qkvd, float* __restrict__ G) {
  constexpr int RS = 264;
  __shared__ unsigned short lds[48 * RS];
  int t = threadIdx.x;
  int nsp = blockIdx.x, h = blockIdx.y, b = blockIdx.z;
  int lane = t & 63, wv = t >> 6, lrow = lane & 15, lhi = lane >> 4;
  f32x4 D00 = {0.f,0.f,0.f,0.f}, D01 = D00, D02 = D00, D11 = D00, D12 = D00, D22 = D00;
  size_t rb = (size_t)b << 14;
  int qb = h * 24, kb = 192 + h * 24;

  for (int rnd = 0; rnd < 4; ++rnd) {
    int n0 = nsp * 1024 + rnd * 256;
    __syncthreads();
#pragma unroll
    for (int part = 0; part < 2; part++) {
      int cb = part ? kb : qb;
#pragma unroll
      for (int ch8 = 0; ch8 < 3; ch8++) {
        short8 v = *reinterpret_cast<const short8*>(
            &qkvd[(rb + n0 + t) * 576 + cb + ch8 * 8]);
#pragma unroll
        for (int j = 0; j < 8; j++)
          lds[(part * 24 + ch8 * 8 + j) * RS + t] = (unsigned short)v[j];
      }
    }
    __syncthreads();
#pragma unroll
    for (int st = 0; st < 2; st++) {
      int noff = (wv * 2 + st) * 32 + lhi * 8;
      short8 f0 = *reinterpret_cast<const short8*>(&lds[(0 + lrow) * RS + noff]);
      short8 f1 = *reinterpret_cast<const short8*>(&lds[(16 + lrow) * RS + noff]);
      short8 f2 = *reinterpret_cast<const short8*>(&lds[(32 + lrow) * RS + noff]);
      D00 = __builtin_amdgcn_mfma_f32_16x16x32_bf16(f0, f0, D00, 0, 0, 0);
      D01 = __builtin_amdgcn_mfma_f32_16x16x32_bf16(f0, f1, D01, 0, 0, 0);
      D02 = __builtin_amdgcn_mfma_f32_16x16x32_bf16(f0, f2, D02, 0, 0, 0);
      D11 = __builtin_amdgcn_mfma_f32_16x16x32_bf16(f1, f1, D11, 0, 0, 0);
      D12 = __builtin_amdgcn_mfma_f32_16x16x32_bf16(f1, f2, D12, 0, 0, 0);
      D22 = __builtin_amdgcn_mfma_f32_16x16x32_bf16(f2, f2, D22, 0, 0, 0);
    }
  }
  float* Gh = G + (size_t)(b * 8 + h) * 48 * 48;
#define EMIT(Dv, i, j)                                                          \
  {                                                                             \
    _Pragma("unroll") for (int r = 0; r < 4; r++)                               \
        atomicAdd(&Gh[(16 * (i) + lhi * 4 + r) * 48 + 16 * (j) + lrow], Dv[r]); \
  }
  EMIT(D00, 0, 0); EMIT(D01, 0, 1); EMIT(D02, 0, 2);
  EMIT(D11, 1, 1); EMIT(D12, 1, 2); EMIT(D22, 2, 2);
#undef EMIT
}

// ---------------------------------------------------------------------------
// softmax of logits built from Gram; A[b][h][c][d]
// ---------------------------------------------------------------------------
__global__ __launch_bounds__(256) void k_attnsm(
    const float* __restrict__ G, const float* __restrict__ temp,
    float* __restrict__ A) {
  int idx = blockIdx.x * 256 + threadIdx.x;   // 768
  if (idx >= 4 * 8 * 24) return;
  int b = idx / (8 * 24);
  int rem = idx - b * 8 * 24;
  int h = rem / 24, c = rem % 24;
  const float* Gh = G + (size_t)(b * 8 + h) * 48 * 48;
  float tpr = temp[h];
  float nq = fmaxf(sqrtf(fmaxf(Gh[c * 48 + c], 0.f)), 1e-12f);
  float lg[24];
  float mx = -1e30f;
#pragma unroll
  for (int d = 0; d < 24; d++) {
    float nk = fmaxf(sqrtf(fmaxf(Gh[(24 + d) * 48 + 24 + d], 0.f)), 1e-12f);
    float l = Gh[c * 48 + 24 + d] / (nq * nk) * tpr;
    lg[d] = l;
    mx = fmaxf(mx, l);
  }
  float s = 0.f;
#pragma unroll
  for (int d = 0; d < 24; d++) { lg[d] = expf(lg[d] - mx); s += lg[d]; }
  float inv = 1.f / s;
  float* Ar = A + (size_t)idx * 24;
#pragma unroll
  for (int d = 0; d < 24; d++) Ar[d] = lg[d] * inv;
}

// ---------------------------------------------------------------------------
// Fold proj_w with per-head attention: M[b][o][h*24+d] (bf16)
// ---------------------------------------------------------------------------
__global__ __launch_bounds__(256) void k_foldM(
    const float* __restrict__ A, const float* __restrict__ P,
    unsigned short* __restrict__ M) {
  int idx = blockIdx.x * 256 + threadIdx.x;   // 4*192*192
  if (idx >= 4 * 192 * 192) return;
  int b = idx / (192 * 192);
  int rem = idx - b * 192 * 192;
  int o = rem / 192, cd = rem % 192;
  int h = cd / 24, d = cd % 24;
  const float* Ah = A + (size_t)(b * 8 + h) * 24 * 24;
  const float* Pr = P + o * 192 + h * 24;
  float s = 0.f;
#pragma unroll
  for (int ch = 0; ch < 24; ch++) s += Pr[ch] * Ah[ch * 24 + d];
  M[idx] = f2bf(s);
}

// ---------------------------------------------------------------------------
extern "C" void kernel_launch(void* const* d_in, const int* in_sizes, int n_in,
                              void* d_out, int out_size, void* d_ws,
                              size_t ws_size, hipStream_t stream) {
  const float* x          = (const float*)d_in[0];
  const float* ln2_w      = (const float*)d_in[1];
  const float* ln2_b      = (const float*)d_in[2];
  const float* qkv_w      = (const float*)d_in[3];
  const float* qkv_dw_w   = (const float*)d_in[4];
  const float* temperature= (const float*)d_in[5];
  const float* attn_proj_w= (const float*)d_in[6];
  const float* ln3_w      = (const float*)d_in[7];
  const float* ln3_b      = (const float*)d_in[8];
  const float* ffn_in_w   = (const float*)d_in[9];
  const float* ffn_dw_w   = (const float*)d_in[10];
  const float* ffn_out_w  = (const float*)d_in[11];

  unsigned char* ws = (unsigned char*)d_ws;
  size_t off = 0;
  auto alloc = [&](size_t bytes) -> void* {
    void* p = ws + off;
    off = (off + bytes + 255) & ~(size_t)255;
    return p;
  };
  (void)alloc(8192);                                       // guard for w=-1 reads
  // S1: qkv fp8 [B][N][576B] (37MB) | xb bf16 @ +75MB (25MB)
  //     -> h fp8 [B][N][1024B] (67MB; disjoint from xb region)
  // S2: y bf16 [N][192] -> qkvd bf16 [N][576] -> g bf16 [N][512]
  unsigned short* S1   = (unsigned short*)alloc(134217728);
  unsigned short* S2   = (unsigned short*)alloc(75497472);
  unsigned short* out1b= (unsigned short*)alloc(25165824);
  unsigned short* y3   = (unsigned short*)alloc(25165824);
  unsigned short* wq   = (unsigned short*)alloc(221184);
  unsigned short* wi   = (unsigned short*)alloc(393216);
  unsigned short* wo   = (unsigned short*)alloc(196608);
  unsigned short* Mw   = (unsigned short*)alloc(294912);
  float*          G    = (float*)alloc(294912);
  float*          Aat  = (float*)alloc(73728);
  float*          dwq  = (float*)alloc(20736);              // 144*9*4*4
  unsigned short* wf8  = (unsigned short*)alloc(18432);     // 128*9*8*2
  unsigned short* xb   = S1 + 37748736;                     // S1 + 75MB region
  unsigned char*  qkv8 = (unsigned char*)S1;                // fp8 [N][576B]
  unsigned char*  h8   = (unsigned char*)S1;                // fp8 [N][1024B]

  k_convert_w<<<768, 256, 0, stream>>>(qkv_w, ffn_in_w, ffn_out_w, qkv_dw_w,
                                       ffn_dw_w, wq, wi, wo, dwq, wf8);
  k_zero<<<288, 256, 0, stream>>>(G, 4 * 8 * 48 * 48);

  // K1: LN2(x) -> y bf16 (S2); also xb = bf16(x)
  k_ln<<<512, 256, 0, stream>>>(x, ln2_w, ln2_b, S2, xb);

  // K2: qkv = y @ wq^T -> qkv8 fp8 [B][N][576B]
  k_gemm<192, 192, 2, 4><<<dim3(64, 3, 4), 512, 0, stream>>>(
      S2, 192, wq, 0, nullptr, nullptr, qkv8, 576);

  // K3: dwconv on qkv8 -> qkvd bf16 (S2)
  k_dwq<<<4608, 256, 0, stream>>>(qkv8, dwq, S2);

  // K4: Gram of [q;k] -> G
  k_gram<<<dim3(16, 8, 4), 256, 0, stream>>>(S2, G);

  // K5: softmax -> Aat ; fold with proj -> M
  k_attnsm<<<3, 256, 0, stream>>>(G, temperature, Aat);
  k_foldM<<<576, 256, 0, stream>>>(Aat, attn_proj_w, Mw);

  // K6: out1b = bf16(xb + M[b]@v), y3 = LN3(out1b)  (wave = 16 rows)
  k_gemm6<<<dim3(128, 4), 512, 0, stream>>>(
      S2 + 384, Mw, xb, ln3_w, ln3_b, out1b, y3);

  // K8: h = y3 @ wi^T -> h8 fp8 [B][N][1024B]  (NB=2, OCHUNK=64: no spills)
  k_gemm<192, 64, 2, 4><<<dim3(64, 16, 4), 512, 0, stream>>>(
      y3, 192, wi, 0, nullptr, nullptr, h8, 1024);

  // K9: dwconv pairs + gelu gate -> g bf16 [B][N][512] (S2)
  k_dwf<<<8192, 256, 0, stream>>>(h8, wf8, S2);

  // K10: d_out = out1b + g @ wo^T  (fp32 [B][192][N])  (OCHUNK=32)
  k_gemm<512, 32, 1, 3><<<dim3(128, 6, 4), 512, 0, stream>>>(
      S2, 512, wo, 0, nullptr, out1b, d_out, 0);
}

// Round 14
// 265.407 us; speedup vs baseline: 1.2391x; 1.2391x over previous
//
#include <hip/hip_runtime.h>
#include <math.h>

// ---------------------------------------------------------------------------
// Restormer-style TransformerBlock on MI355X (gfx950)
// B=4, C=192, H=W=128, N=HW=16384, heads=8, ch/head=24, hidden=510
// Intermediates: y/xb/out1b/y3/qkvd/g bf16 [B][N][C]; qkv/h fp8-e4m3 (OCP).
// Residual: x fp32 [C][N] in, d_out fp32 [C][N]. LN3 fused into K6.
// fp8 GEMM epilogues use a 4x4 lane transpose so stores are full 64B lines.
// ---------------------------------------------------------------------------

typedef __attribute__((ext_vector_type(8))) short short8;
typedef __attribute__((ext_vector_type(4))) short short4v;
typedef __attribute__((ext_vector_type(4))) float f32x4;
typedef __attribute__((ext_vector_type(2))) float f32x2;
typedef __attribute__((ext_vector_type(4))) int int4v;

#define DEVI __device__ __forceinline__

DEVI unsigned short f2bf(float f) {
  union { float f; unsigned u; } v; v.f = f;
  unsigned r = v.u + 0x7fffu + ((v.u >> 16) & 1u);   // RNE
  return (unsigned short)(r >> 16);
}
DEVI float bf2f(unsigned short h) {
  union { unsigned u; float f; } v; v.u = ((unsigned)h) << 16;
  return v.f;
}
// branch-free GELU, exp2-folded tanh form; inf-safe (e=inf -> rcp=0 -> x*1)
DEVI float gelu_f(float x) {
  float t = x * (2.30258509f + 0.10296501f * x * x);
  float e = exp2f(t);
  return x * (1.f - __builtin_amdgcn_rcpf(e + 1.f));
}
// 4x4 transpose of one int per (lhi group); after call lane lhi holds the
// 16B-contiguous piece (gt*4+lhi)*16 .. +16 of its row.
DEVI void xpose4(int u[4], int lhi) {
  bool b0 = lhi & 1;
  int a = b0 ? u[0] : u[1];
  int b = b0 ? u[2] : u[3];
  a = __shfl_xor(a, 16, 64);
  b = __shfl_xor(b, 16, 64);
  if (b0) { u[0] = a; u[2] = b; } else { u[1] = a; u[3] = b; }
  bool b1 = lhi & 2;
  int c = b1 ? u[0] : u[2];
  int d = b1 ? u[1] : u[3];
  c = __shfl_xor(c, 32, 64);
  d = __shfl_xor(d, 32, 64);
  if (b1) { u[0] = c; u[1] = d; } else { u[2] = c; u[3] = d; }
}

// ---------------------------------------------------------------------------
// K0: convert + zero-pad weights to bf16; pack dw-conv weights.
//  dwq [144 g][9 q][4 j] f32 ; wf8 [128 g][9 q][8 sj] bf16 (ch>=510 -> 0)
// ---------------------------------------------------------------------------
__global__ __launch_bounds__(256) void k_convert_w(
    const float* __restrict__ qkv_w, const float* __restrict__ ffn_in_w,
    const float* __restrict__ ffn_out_w, const float* __restrict__ qkv_dw_w,
    const float* __restrict__ ffn_dw_w,
    unsigned short* __restrict__ wq, unsigned short* __restrict__ wi,
    unsigned short* __restrict__ wo, float* __restrict__ dwq,
    unsigned short* __restrict__ wf8) {
  int idx = blockIdx.x * 256 + threadIdx.x;
  if (idx < 576 * 192) wq[idx] = f2bf(qkv_w[idx]);
  if (idx < 1024 * 192) {
    int o = idx / 192, c = idx - o * 192;
    int src = (o < 510) ? o : ((o >= 512 && o < 1022) ? o - 2 : -1);
    wi[idx] = (src >= 0) ? f2bf(ffn_in_w[src * 192 + c]) : (unsigned short)0;
  }
  if (idx < 192 * 512) {
    int o = idx >> 9, c = idx & 511;
    wo[idx] = (c < 510) ? f2bf(ffn_out_w[o * 510 + c]) : (unsigned short)0;
  }
  if (idx < 144 * 36) {
    int g = idx / 36, r = idx - g * 36;
    int q = r >> 2, j = r & 3;
    dwq[idx] = qkv_dw_w[(g * 4 + j) * 9 + q];
  }
  if (idx < 128 * 72) {
    int g = idx / 72, r = idx - g * 72;
    int q = r >> 3, sj = r & 7, s = sj >> 2, j = sj & 3;
    int ch = g * 4 + j;
    wf8[idx] = (ch < 510) ? f2bf(ffn_dw_w[(s ? 510 + ch : ch) * 9 + q])
                          : (unsigned short)0;
  }
}

__global__ __launch_bounds__(256) void k_zero(float* __restrict__ p, int n) {
  int i = blockIdx.x * 256 + threadIdx.x;
  if (i < n) p[i] = 0.f;
}

// ---------------------------------------------------------------------------
// LN2: fp32 [B][192][N] -> y bf16 [B][N][192]; also emits xb = bf16(x).
// ---------------------------------------------------------------------------
__global__ __launch_bounds__(256) void k_ln(
    const float* __restrict__ x, const float* __restrict__ g,
    const float* __restrict__ bta, unsigned short* __restrict__ y,
    unsigned short* __restrict__ xb) {
  int idx = blockIdx.x * 256 + threadIdx.x;   // 2 * B*N = 131072
  int half = idx & 1;
  int n = idx >> 1;
  int b = n >> 14, nn = n & 16383;
  int c0 = half * 96;
  const float* px = x + (((size_t)b * 192 + c0) << 14) + nn;
  float v[96];
  float s = 0.f, ss = 0.f;
#pragma unroll
  for (int j = 0; j < 96; j++) {
    v[j] = px[(size_t)j << 14];
    s += v[j]; ss += v[j] * v[j];
  }
  s += __shfl_xor(s, 1, 64);
  ss += __shfl_xor(ss, 1, 64);
  float mu = s * (1.f / 192.f);
  float var = ss * (1.f / 192.f) - mu * mu;
  float rs = rsqrtf(var + 1e-5f);
  size_t rowb = ((((size_t)b << 14) + nn) * 192) + c0;
  unsigned short* py = y + rowb;
  unsigned short* pxb = xb + rowb;
#pragma unroll
  for (int j8 = 0; j8 < 12; j8++) {
    short8 o8, x8;
#pragma unroll
    for (int k = 0; k < 8; k++) {
      int c = c0 + j8 * 8 + k;
      float f = v[j8 * 8 + k];
      o8[k] = (short)f2bf((f - mu) * rs * g[c] + bta[c]);
      x8[k] = (short)f2bf(f);
    }
    *reinterpret_cast<short8*>(py + j8 * 8) = o8;
    *reinterpret_cast<short8*>(pxb + j8 * 8) = x8;
  }
}

// ---------------------------------------------------------------------------
// GEMM: out[o][n] = sum_c W[o][c] * in[n][c]
//  EPI 3: fp32 store d_out[(b*192+o)<<14|nn] = bf2f(residB[n*192+o]) + acc
//  EPI 4: fp8 (e4m3) store to out[N][rsout] (rsout bytes), 16B/lane via
//         grouped 4x4 lane transpose (full 64B line per row per instr)
// ---------------------------------------------------------------------------
template <int C, int OCHUNK, int NB, int EPI>
__global__ __launch_bounds__(512) void k_gemm(
    const unsigned short* __restrict__ in, int rsin,
    const unsigned short* __restrict__ W, int wbs,
    const float* __restrict__ residF, const unsigned short* __restrict__ residB,
    void* __restrict__ outp, int rsout) {
  constexpr int SLOTS = C / 8;
  __shared__ unsigned short lds[OCHUNK * C];
  int t = threadIdx.x;
  int b = blockIdx.z;
  int ocb = blockIdx.y * OCHUNK;
  int wv = t >> 6, lane = t & 63, lrow = lane & 15, lhi = lane >> 4;

  const unsigned short* Wb = W + (size_t)b * wbs;
#pragma unroll
  for (int i = t; i < OCHUNK * SLOTS; i += 512) {
    int o = i / SLOTS, s = i - o * SLOTS;
    short8 v = *reinterpret_cast<const short8*>(&Wb[(size_t)(ocb + o) * C + s * 8]);
    *reinterpret_cast<short8*>(&lds[(o * SLOTS + (s ^ (o & 7))) * 8]) = v;
  }

  size_t nbase = ((size_t)b << 14) + blockIdx.x * (128 * NB) + wv * (16 * NB);
  short8 bf[NB][C / 32];
#pragma unroll
  for (int nb = 0; nb < NB; nb++) {
    const unsigned short* prow = in + (nbase + nb * 16 + lrow) * rsin + lhi * 8;
#pragma unroll
    for (int k = 0; k < C / 32; k++)
      bf[nb][k] = *reinterpret_cast<const short8*>(prow + k * 32);
  }
  __syncthreads();

  if (EPI == 4) {
    for (int gt = 0; gt < OCHUNK / 64; ++gt) {
      int ubuf[NB][4];
#pragma unroll
      for (int j = 0; j < 4; ++j) {
        int ot = gt * 4 + j;
        f32x4 acc[NB];
#pragma unroll
        for (int nb = 0; nb < NB; nb++) acc[nb] = (f32x4){0.f, 0.f, 0.f, 0.f};
        int orow = ot * 16 + lrow;
#pragma unroll
        for (int k = 0; k < C / 32; k++) {
          short8 a = *reinterpret_cast<const short8*>(
              &lds[(orow * SLOTS + ((k * 4 + lhi) ^ (lrow & 7))) * 8]);
#pragma unroll
          for (int nb = 0; nb < NB; nb++)
            acc[nb] = __builtin_amdgcn_mfma_f32_16x16x32_bf16(a, bf[nb][k], acc[nb], 0, 0, 0);
        }
#pragma unroll
        for (int nb = 0; nb < NB; nb++) {
          int u = 0;
          u = __builtin_amdgcn_cvt_pk_fp8_f32(acc[nb][0], acc[nb][1], u, false);
          u = __builtin_amdgcn_cvt_pk_fp8_f32(acc[nb][2], acc[nb][3], u, true);
          ubuf[nb][j] = u;
        }
      }
#pragma unroll
      for (int nb = 0; nb < NB; nb++) {
        xpose4(ubuf[nb], lhi);
        size_t n = nbase + nb * 16 + lrow;
        *reinterpret_cast<int4v*>((unsigned char*)outp + n * (size_t)rsout +
                                  ocb + gt * 64 + lhi * 16) =
            (int4v){ubuf[nb][0], ubuf[nb][1], ubuf[nb][2], ubuf[nb][3]};
      }
    }
  } else {
    for (int ot = 0; ot < OCHUNK / 16; ++ot) {
      f32x4 acc[NB];
#pragma unroll
      for (int nb = 0; nb < NB; nb++) acc[nb] = (f32x4){0.f, 0.f, 0.f, 0.f};
      int orow = ot * 16 + lrow;
#pragma unroll
      for (int k = 0; k < C / 32; k++) {
        short8 a = *reinterpret_cast<const short8*>(
            &lds[(orow * SLOTS + ((k * 4 + lhi) ^ (lrow & 7))) * 8]);
#pragma unroll
        for (int nb = 0; nb < NB; nb++)
          acc[nb] = __builtin_amdgcn_mfma_f32_16x16x32_bf16(a, bf[nb][k], acc[nb], 0, 0, 0);
      }
#pragma unroll
      for (int nb = 0; nb < NB; nb++) {
        size_t n = nbase + nb * 16 + lrow;   // includes b*16384
        int obase = ocb + ot * 16 + lhi * 4;
        int nn = (int)(n & 16383);
        short4v rb = *reinterpret_cast<const short4v*>(residB + n * 192 + obase);
#pragma unroll
        for (int r = 0; r < 4; r++) {
          size_t idx = (((size_t)(b * 192 + obase + r)) << 14) + nn;
          ((float*)outp)[idx] = bf2f((unsigned short)rb[r]) + acc[nb][r];
        }
      }
    }
  }
}

// ---------------------------------------------------------------------------
// K6: z = M[b] @ v + xb ; out1b = bf16(z) ; y3 = bf16(LN3(z)).  LN3 once.
// (round-12 proven config: wave = 32 rows, grid (64, 4))
// ---------------------------------------------------------------------------
__global__ __launch_bounds__(512) void k_gemm6(
    const unsigned short* __restrict__ in,    // v rows: qkvd+384, rsin=576
    const unsigned short* __restrict__ Mw,    // [b][192][192]
    const unsigned short* __restrict__ xb,    // bf16 [B*N][192] residual
    const float* __restrict__ lg, const float* __restrict__ lb,
    unsigned short* __restrict__ out1b,       // [B*N][192]
    unsigned short* __restrict__ y3) {        // [B*N][192]
  constexpr int SLOTS = 24;
  __shared__ unsigned short lds[192 * 192];
  int t = threadIdx.x;
  int b = blockIdx.y;
  int wv = t >> 6, lane = t & 63, lrow = lane & 15, lhi = lane >> 4;

  const unsigned short* Wb = Mw + (size_t)b * 192 * 192;
#pragma unroll
  for (int i = t; i < 192 * SLOTS; i += 512) {
    int o = i / SLOTS, s = i - o * SLOTS;
    short8 v = *reinterpret_cast<const short8*>(&Wb[o * 192 + s * 8]);
    *reinterpret_cast<short8*>(&lds[(o * SLOTS + (s ^ (o & 7))) * 8]) = v;
  }

  size_t nbase = ((size_t)b << 14) + blockIdx.x * 256 + wv * 32;
  short8 bf[2][6];
#pragma unroll
  for (int nb = 0; nb < 2; nb++) {
    const unsigned short* prow = in + (nbase + nb * 16 + lrow) * 576 + lhi * 8;
#pragma unroll
    for (int k = 0; k < 6; k++)
      bf[nb][k] = *reinterpret_cast<const short8*>(prow + k * 32);
  }
  __syncthreads();

  short4v zs[12][2];
  float s[2] = {0.f, 0.f}, ss[2] = {0.f, 0.f};
#pragma unroll
  for (int ot = 0; ot < 12; ++ot) {
    f32x4 acc[2];
    acc[0] = (f32x4){0.f, 0.f, 0.f, 0.f};
    acc[1] = acc[0];
    int orow = ot * 16 + lrow;
#pragma unroll
    for (int k = 0; k < 6; k++) {
      short8 a = *reinterpret_cast<const short8*>(
          &lds[(orow * SLOTS + ((k * 4 + lhi) ^ (lrow & 7))) * 8]);
      acc[0] = __builtin_amdgcn_mfma_f32_16x16x32_bf16(a, bf[0][k], acc[0], 0, 0, 0);
      acc[1] = __builtin_amdgcn_mfma_f32_16x16x32_bf16(a, bf[1][k], acc[1], 0, 0, 0);
    }
    int obase = ot * 16 + lhi * 4;
#pragma unroll
    for (int nb = 0; nb < 2; nb++) {
      size_t n = nbase + nb * 16 + lrow;
      short4v xv = *reinterpret_cast<const short4v*>(xb + n * 192 + obase);
      short4v pk;
#pragma unroll
      for (int r = 0; r < 4; r++) {
        float val = bf2f((unsigned short)xv[r]) + acc[nb][r];
        s[nb] += val; ss[nb] += val * val;
        pk[r] = (short)f2bf(val);
      }
      *reinterpret_cast<short4v*>(out1b + n * 192 + obase) = pk;
      zs[ot][nb] = pk;
    }
  }

  float mu[2], rs[2];
#pragma unroll
  for (int nb = 0; nb < 2; nb++) {
    float sv = s[nb], sq = ss[nb];
    sv += __shfl_xor(sv, 16, 64);  sv += __shfl_xor(sv, 32, 64);
    sq += __shfl_xor(sq, 16, 64); sq += __shfl_xor(sq, 32, 64);
    mu[nb] = sv * (1.f / 192.f);
    float var = sq * (1.f / 192.f) - mu[nb] * mu[nb];
    rs[nb] = rsqrtf(var + 1e-5f);
  }
#pragma unroll
  for (int ot = 0; ot < 12; ++ot) {
    int c0 = ot * 16 + lhi * 4;
    f32x4 g4 = *reinterpret_cast<const f32x4*>(lg + c0);
    f32x4 b4 = *reinterpret_cast<const f32x4*>(lb + c0);
#pragma unroll
    for (int nb = 0; nb < 2; nb++) {
      size_t n = nbase + nb * 16 + lrow;
      short4v pk;
#pragma unroll
      for (int r = 0; r < 4; r++) {
        float f = bf2f((unsigned short)zs[ot][nb][r]);
        pk[r] = (short)f2bf((f - mu[nb]) * rs[nb] * g4[r] + b4[r]);
      }
      *reinterpret_cast<short4v*>(y3 + n * 192 + c0) = pk;
    }
  }
}

// ---------------------------------------------------------------------------
// Depthwise 3x3 (pad 1) for qkv path: in fp8 [N][576B], out bf16 [N][576].
// Thread = 4 ch x 4 w x 2 h. Lane dim = channel group (coalesced).
// ---------------------------------------------------------------------------
__global__ __launch_bounds__(256) void k_dwq(
    const unsigned char* __restrict__ in, const float* __restrict__ wp,
    unsigned short* __restrict__ out) {
  constexpr int RSI = 576;   // bytes per n-row
  int idx = blockIdx.x * 256 + threadIdx.x;   // 144 g * 32 w4 * 64 h2 * 4 b
  int g = idx % 144;
  int rest = idx / 144;
  int w4 = rest & 31, h2 = (rest >> 5) & 63, b = rest >> 11;
  int h0 = h2 * 2, w0 = w4 * 4, ch0 = g * 4;
  bool vm = (h0 > 0), vp = (h0 < 126);
  bool zl = (w4 == 0), zr = (w4 == 31);

  const unsigned char* p1 = in + (((size_t)b << 14) + h0 * 128 + w0) * RSI + ch0;
  const unsigned char* pr0 = vm ? p1 - 128 * RSI : p1;
  const unsigned char* pr2 = p1 + 128 * RSI;
  const unsigned char* pr3 = vp ? p1 + 256 * RSI : p1;

  unsigned m[4][6];
#pragma unroll
  for (int k = 0; k < 6; k++) {
    m[0][k] = *reinterpret_cast<const unsigned*>(pr0 + (k - 1) * RSI);
    m[1][k] = *reinterpret_cast<const unsigned*>(p1 + (k - 1) * RSI);
    m[2][k] = *reinterpret_cast<const unsigned*>(pr2 + (k - 1) * RSI);
    m[3][k] = *reinterpret_cast<const unsigned*>(pr3 + (k - 1) * RSI);
  }
  f32x4 wv4[9];
#pragma unroll
  for (int q = 0; q < 9; q++)
    wv4[q] = *reinterpret_cast<const f32x4*>(&wp[(g * 9 + q) * 4]);

  if (!vm) {
#pragma unroll
    for (int k = 0; k < 6; k++) m[0][k] = 0u;
  }
  if (!vp) {
#pragma unroll
    for (int k = 0; k < 6; k++) m[3][k] = 0u;
  }
  if (zl) {
#pragma unroll
    for (int r = 0; r < 4; r++) m[r][0] = 0u;
  }
  if (zr) {
#pragma unroll
    for (int r = 0; r < 4; r++) m[r][5] = 0u;
  }

  f32x2 acc[2][4][2];
#pragma unroll
  for (int ho = 0; ho < 2; ho++)
#pragma unroll
    for (int wo = 0; wo < 4; wo++)
#pragma unroll
      for (int p = 0; p < 2; p++) acc[ho][wo][p] = (f32x2){0.f, 0.f};

#pragma unroll
  for (int r = 0; r < 4; r++) {
    f32x2 f[6][2];
#pragma unroll
    for (int k = 0; k < 6; k++) {
      f[k][0] = __builtin_amdgcn_cvt_pk_f32_fp8((int)m[r][k], false);
      f[k][1] = __builtin_amdgcn_cvt_pk_f32_fp8((int)m[r][k], true);
    }
#pragma unroll
    for (int ho = 0; ho < 2; ho++) {
      int dh = r - ho;
      if (dh < 0 || dh > 2) continue;   // folds at compile time
#pragma unroll
      for (int dw = 0; dw < 3; dw++) {
        f32x4 w4v = wv4[dh * 3 + dw];
        f32x2 wa = {w4v[0], w4v[1]}, wb = {w4v[2], w4v[3]};
#pragma unroll
        for (int wo = 0; wo < 4; wo++) {
          acc[ho][wo][0] += wa * f[wo + dw][0];
          acc[ho][wo][1] += wb * f[wo + dw][1];
        }
      }
    }
  }

  unsigned short* ob = out + (((size_t)b << 14) + h0 * 128 + w0) * 576 + ch0;
#pragma unroll
  for (int ho = 0; ho < 2; ho++)
#pragma unroll
    for (int wo = 0; wo < 4; wo++) {
      short4v o4;
      o4[0] = (short)f2bf(acc[ho][wo][0].x);
      o4[1] = (short)f2bf(acc[ho][wo][0].y);
      o4[2] = (short)f2bf(acc[ho][wo][1].x);
      o4[3] = (short)f2bf(acc[ho][wo][1].y);
      *reinterpret_cast<short4v*>(ob + (ho * 128 + wo) * 576) = o4;
    }
}

// ---------------------------------------------------------------------------
// Depthwise 3x3 + GELU gate for FFN: in fp8 [N][1024B] cols c & 512+c
// -> out bf16 [N][512]. Thread = 4 ch x 2 w x 2 h, both sets.
// ---------------------------------------------------------------------------
__global__ __launch_bounds__(256) void k_dwf(
    const unsigned char* __restrict__ in, const unsigned short* __restrict__ wp8,
    unsigned short* __restrict__ out) {
  constexpr int RSI = 1024;   // bytes per n-row
  int idx = blockIdx.x * 256 + threadIdx.x;   // 128 g * 64 w2 * 64 h2 * 4 b
  int g = idx & 127;
  int rest = idx >> 7;
  int w2 = rest & 63, h2 = (rest >> 6) & 63, b = rest >> 12;
  int w0 = w2 * 2, h0 = h2 * 2, ch0 = g * 4;
  bool vm = (h0 > 0), vp = (h0 < 126);
  bool zl = (w2 == 0), zr = (w2 == 63);

  const unsigned char* p1 = in + (((size_t)b << 14) + h0 * 128 + w0) * RSI + ch0;
  const unsigned char* pr0 = vm ? p1 - 128 * RSI : p1;
  const unsigned char* pr2 = p1 + 128 * RSI;
  const unsigned char* pr3 = vp ? p1 + 256 * RSI : p1;

  unsigned m[2][4][4];   // [set][row][wchunk: w-1..w+2]
#pragma unroll
  for (int s = 0; s < 2; s++) {
    int co = s * 512;
#pragma unroll
    for (int k = 0; k < 4; k++) {
      m[s][0][k] = *reinterpret_cast<const unsigned*>(pr0 + (k - 1) * RSI + co);
      m[s][1][k] = *reinterpret_cast<const unsigned*>(p1 + (k - 1) * RSI + co);
      m[s][2][k] = *reinterpret_cast<const unsigned*>(pr2 + (k - 1) * RSI + co);
      m[s][3][k] = *reinterpret_cast<const unsigned*>(pr3 + (k - 1) * RSI + co);
    }
  }
#pragma unroll
  for (int s = 0; s < 2; s++) {
    if (!vm) {
#pragma unroll
      for (int k = 0; k < 4; k++) m[s][0][k] = 0u;
    }
    if (!vp) {
#pragma unroll
      for (int k = 0; k < 4; k++) m[s][3][k] = 0u;
    }
    if (zl) {
#pragma unroll
      for (int r = 0; r < 4; r++) m[s][r][0] = 0u;
    }
    if (zr) {
#pragma unroll
      for (int r = 0; r < 4; r++) m[s][r][3] = 0u;
    }
  }

  f32x2 acc1[2][2][2], acc2[2][2][2];   // [ho][wo][pair]
#pragma unroll
  for (int ho = 0; ho < 2; ho++)
#pragma unroll
    for (int wo = 0; wo < 2; wo++)
#pragma unroll
      for (int p = 0; p < 2; p++) {
        acc1[ho][wo][p] = (f32x2){0.f, 0.f};
        acc2[ho][wo][p] = (f32x2){0.f, 0.f};
      }

#pragma unroll
  for (int s = 0; s < 2; s++) {
#pragma unroll
    for (int r = 0; r < 4; r++) {
      f32x2 f[4][2];
#pragma unroll
      for (int k = 0; k < 4; k++) {
        f[k][0] = __builtin_amdgcn_cvt_pk_f32_fp8((int)m[s][r][k], false);
        f[k][1] = __builtin_amdgcn_cvt_pk_f32_fp8((int)m[s][r][k], true);
      }
#pragma unroll
      for (int ho = 0; ho < 2; ho++) {
        int dh = r - ho;
        if (dh < 0 || dh > 2) continue;
#pragma unroll
        for (int dw = 0; dw < 3; dw++) {
          int q = dh * 3 + dw;
          short4v wr = *reinterpret_cast<const short4v*>(
              wp8 + (g * 9 + q) * 8 + s * 4);
          f32x2 wa = {bf2f((unsigned short)wr[0]), bf2f((unsigned short)wr[1])};
          f32x2 wb = {bf2f((unsigned short)wr[2]), bf2f((unsigned short)wr[3])};
#pragma unroll
          for (int wo = 0; wo < 2; wo++) {
            if (s == 0) {
              acc1[ho][wo][0] += wa * f[wo + dw][0];
              acc1[ho][wo][1] += wb * f[wo + dw][1];
            } else {
              acc2[ho][wo][0] += wa * f[wo + dw][0];
              acc2[ho][wo][1] += wb * f[wo + dw][1];
            }
          }
        }
      }
    }
  }

  unsigned short* ob = out + (((size_t)b << 14) + h0 * 128 + w0) * 512 + ch0;
#pragma unroll
  for (int ho = 0; ho < 2; ho++)
#pragma unroll
    for (int wo = 0; wo < 2; wo++) {
      float x1v[4] = {acc1[ho][wo][0].x, acc1[ho][wo][0].y,
                      acc1[ho][wo][1].x, acc1[ho][wo][1].y};
      float x2v[4] = {acc2[ho][wo][0].x, acc2[ho][wo][0].y,
                      acc2[ho][wo][1].x, acc2[ho][wo][1].y};
      short4v o4;
#pragma unroll
      for (int j = 0; j < 4; j++)
        o4[j] = (short)f2bf(gelu_f(x1v[j]) * x2v[j]);
      *reinterpret_cast<short4v*>(ob + (ho * 128 + wo) * 512) = o4;
    }
}

// ---------------------------------------------------------------------------
// Gram: G[b][h][48][48] += stacked.stacked^T (rows [q_h;k_h]), over n.
// ---------------------------------------------------------------------------
__global__ __launch_bounds__(256) void k_gram(
    const unsigned short* __restrict__ qkvd, float* __restrict__ G) {
  constexpr int RS = 264;
  __shared__ unsigned short lds[48 * RS];
  int t = threadIdx.x;
  int nsp = blockIdx.x, h = blockIdx.y, b = blockIdx.z;
  int lane = t & 63, wv = t >> 6, lrow = lane & 15, lhi = lane >> 4;
  f32x4 D00 = {0.f,0.f,0.f,0.f}, D01 = D00, D02 = D00, D11 = D00, D12 = D00, D22 = D00;
  size_t rb = (size_t)b << 14;
  int qb = h * 24, kb = 192 + h * 24;

  for (int rnd = 0; rnd < 4; ++rnd) {
    int n0 = nsp * 1024 + rnd * 256;
    __syncthreads();
#pragma unroll
    for (int part = 0; part < 2; part++) {
      int cb = part ? kb : qb;
#pragma unroll
      for (int ch8 = 0; ch8 < 3; ch8++) {
        short8 v = *reinterpret_cast<const short8*>(
            &qkvd[(rb + n0 + t) * 576 + cb + ch8 * 8]);
#pragma unroll
        for (int j = 0; j < 8; j++)
          lds[(part * 24 + ch8 * 8 + j) * RS + t] = (unsigned short)v[j];
      }
    }
    __syncthreads();
#pragma unroll
    for (int st = 0; st < 2; st++) {
      int noff = (wv * 2 + st) * 32 + lhi * 8;
      short8 f0 = *reinterpret_cast<const short8*>(&lds[(0 + lrow) * RS + noff]);
      short8 f1 = *reinterpret_cast<const short8*>(&lds[(16 + lrow) * RS + noff]);
      short8 f2 = *reinterpret_cast<const short8*>(&lds[(32 + lrow) * RS + noff]);
      D00 = __builtin_amdgcn_mfma_f32_16x16x32_bf16(f0, f0, D00, 0, 0, 0);
      D01 = __builtin_amdgcn_mfma_f32_16x16x32_bf16(f0, f1, D01, 0, 0, 0);
      D02 = __builtin_amdgcn_mfma_f32_16x16x32_bf16(f0, f2, D02, 0, 0, 0);
      D11 = __builtin_amdgcn_mfma_f32_16x16x32_bf16(f1, f1, D11, 0, 0, 0);
      D12 = __builtin_amdgcn_mfma_f32_16x16x32_bf16(f1, f2, D12, 0, 0, 0);
      D22 = __builtin_amdgcn_mfma_f32_16x16x32_bf16(f2, f2, D22, 0, 0, 0);
    }
  }
  float* Gh = G + (size_t)(b * 8 + h) * 48 * 48;
#define EMIT(Dv, i, j)                                                          \
  {                                                                             \
    _Pragma("unroll") for (int r = 0; r < 4; r++)                               \
        atomicAdd(&Gh[(16 * (i) + lhi * 4 + r) * 48 + 16 * (j) + lrow], Dv[r]); \
  }
  EMIT(D00, 0, 0); EMIT(D01, 0, 1); EMIT(D02, 0, 2);
  EMIT(D11, 1, 1); EMIT(D12, 1, 2); EMIT(D22, 2, 2);
#undef EMIT
}

// ---------------------------------------------------------------------------
// softmax of logits built from Gram; A[b][h][c][d]
// ---------------------------------------------------------------------------
__global__ __launch_bounds__(256) void k_attnsm(
    const float* __restrict__ G, const float* __restrict__ temp,
    float* __restrict__ A) {
  int idx = blockIdx.x * 256 + threadIdx.x;   // 768
  if (idx >= 4 * 8 * 24) return;
  int b = idx / (8 * 24);
  int rem = idx - b * 8 * 24;
  int h = rem / 24, c = rem % 24;
  const float* Gh = G + (size_t)(b * 8 + h) * 48 * 48;
  float tpr = temp[h];
  float nq = fmaxf(sqrtf(fmaxf(Gh[c * 48 + c], 0.f)), 1e-12f);
  float lg[24];
  float mx = -1e30f;
#pragma unroll
  for (int d = 0; d < 24; d++) {
    float nk = fmaxf(sqrtf(fmaxf(Gh[(24 + d) * 48 + 24 + d], 0.f)), 1e-12f);
    float l = Gh[c * 48 + 24 + d] / (nq * nk) * tpr;
    lg[d] = l;
    mx = fmaxf(mx, l);
  }
  float s = 0.f;
#pragma unroll
  for (int d = 0; d < 24; d++) { lg[d] = expf(lg[d] - mx); s += lg[d]; }
  float inv = 1.f / s;
  float* Ar = A + (size_t)idx * 24;
#pragma unroll
  for (int d = 0; d < 24; d++) Ar[d] = lg[d] * inv;
}

// ---------------------------------------------------------------------------
// Fold proj_w with per-head attention: M[b][o][h*24+d] (bf16)
// ---------------------------------------------------------------------------
__global__ __launch_bounds__(256) void k_foldM(
    const float* __restrict__ A, const float* __restrict__ P,
    unsigned short* __restrict__ M) {
  int idx = blockIdx.x * 256 + threadIdx.x;   // 4*192*192
  if (idx >= 4 * 192 * 192) return;
  int b = idx / (192 * 192);
  int rem = idx - b * 192 * 192;
  int o = rem / 192, cd = rem % 192;
  int h = cd / 24, d = cd % 24;
  const float* Ah = A + (size_t)(b * 8 + h) * 24 * 24;
  const float* Pr = P + o * 192 + h * 24;
  float s = 0.f;
#pragma unroll
  for (int ch = 0; ch < 24; ch++) s += Pr[ch] * Ah[ch * 24 + d];
  M[idx] = f2bf(s);
}

// ---------------------------------------------------------------------------
extern "C" void kernel_launch(void* const* d_in, const int* in_sizes, int n_in,
                              void* d_out, int out_size, void* d_ws,
                              size_t ws_size, hipStream_t stream) {
  const float* x          = (const float*)d_in[0];
  const float* ln2_w      = (const float*)d_in[1];
  const float* ln2_b      = (const float*)d_in[2];
  const float* qkv_w      = (const float*)d_in[3];
  const float* qkv_dw_w   = (const float*)d_in[4];
  const float* temperature= (const float*)d_in[5];
  const float* attn_proj_w= (const float*)d_in[6];
  const float* ln3_w      = (const float*)d_in[7];
  const float* ln3_b      = (const float*)d_in[8];
  const float* ffn_in_w   = (const float*)d_in[9];
  const float* ffn_dw_w   = (const float*)d_in[10];
  const float* ffn_out_w  = (const float*)d_in[11];

  unsigned char* ws = (unsigned char*)d_ws;
  size_t off = 0;
  auto alloc = [&](size_t bytes) -> void* {
    void* p = ws + off;
    off = (off + bytes + 255) & ~(size_t)255;
    return p;
  };
  (void)alloc(8192);                                       // guard for w=-1 reads
  // S1: qkv fp8 [B][N][576B] (37MB) | xb bf16 @ +75MB (25MB)
  //     -> h fp8 [B][N][1024B] (67MB; disjoint from xb region)
  // S2: y bf16 [N][192] -> qkvd bf16 [N][576] -> g bf16 [N][512]
  unsigned short* S1   = (unsigned short*)alloc(134217728);
  unsigned short* S2   = (unsigned short*)alloc(75497472);
  unsigned short* out1b= (unsigned short*)alloc(25165824);
  unsigned short* y3   = (unsigned short*)alloc(25165824);
  unsigned short* wq   = (unsigned short*)alloc(221184);
  unsigned short* wi   = (unsigned short*)alloc(393216);
  unsigned short* wo   = (unsigned short*)alloc(196608);
  unsigned short* Mw   = (unsigned short*)alloc(294912);
  float*          G    = (float*)alloc(294912);
  float*          Aat  = (float*)alloc(73728);
  float*          dwq  = (float*)alloc(20736);              // 144*9*4*4
  unsigned short* wf8  = (unsigned short*)alloc(18432);     // 128*9*8*2
  unsigned short* xb   = S1 + 37748736;                     // S1 + 75MB region
  unsigned char*  qkv8 = (unsigned char*)S1;                // fp8 [N][576B]
  unsigned char*  h8   = (unsigned char*)S1;                // fp8 [N][1024B]

  k_convert_w<<<768, 256, 0, stream>>>(qkv_w, ffn_in_w, ffn_out_w, qkv_dw_w,
                                       ffn_dw_w, wq, wi, wo, dwq, wf8);
  k_zero<<<288, 256, 0, stream>>>(G, 4 * 8 * 48 * 48);

  // K1: LN2(x) -> y bf16 (S2); also xb = bf16(x)
  k_ln<<<512, 256, 0, stream>>>(x, ln2_w, ln2_b, S2, xb);

  // K2: qkv = y @ wq^T -> qkv8 fp8 [B][N][576B] (transposed 16B stores)
  k_gemm<192, 192, 2, 4><<<dim3(64, 3, 4), 512, 0, stream>>>(
      S2, 192, wq, 0, nullptr, nullptr, qkv8, 576);

  // K3: dwconv on qkv8 -> qkvd bf16 (S2)
  k_dwq<<<4608, 256, 0, stream>>>(qkv8, dwq, S2);

  // K4: Gram of [q;k] -> G
  k_gram<<<dim3(16, 8, 4), 256, 0, stream>>>(S2, G);

  // K5: softmax -> Aat ; fold with proj -> M
  k_attnsm<<<3, 256, 0, stream>>>(G, temperature, Aat);
  k_foldM<<<576, 256, 0, stream>>>(Aat, attn_proj_w, Mw);

  // K6: out1b = bf16(xb + M[b]@v), y3 = LN3(out1b)  (r12 config)
  k_gemm6<<<dim3(64, 4), 512, 0, stream>>>(
      S2 + 384, Mw, xb, ln3_w, ln3_b, out1b, y3);

  // K8: h = y3 @ wi^T -> h8 fp8 [B][N][1024B] (OCHUNK=128, NB=2, xposed st)
  k_gemm<192, 128, 2, 4><<<dim3(64, 8, 4), 512, 0, stream>>>(
      y3, 192, wi, 0, nullptr, nullptr, h8, 1024);

  // K9: dwconv pairs + gelu gate -> g bf16 [B][N][512] (S2)
  k_dwf<<<8192, 256, 0, stream>>>(h8, wf8, S2);

  // K10: d_out = out1b + g @ wo^T  (fp32 [B][192][N])  (r12 config)
  k_gemm<512, 64, 1, 3><<<dim3(128, 3, 4), 512, 0, stream>>>(
      S2, 512, wo, 0, nullptr, out1b, d_out, 0);
}